// Round 2
// baseline (484.179 us; speedup 1.0000x reference)
//
#include <hip/hip_runtime.h>
#include <hip/hip_bf16.h>
#include <math.h>

// Problem constants
#define NNODES 200000
#define NGRAPH 100
#define HD     128      // H == NF == 128
#define NCH    3        // virtual channels
#define BN     64       // nodes per block
#define EROWS  (BN*NCH) // 192 e-rows per block
#define ESTR   136      // padded LDS row stride (bf16 elems): 272 B = 16B-aligned, 2-way banks (free)

typedef short short8 __attribute__((ext_vector_type(8)));
typedef float f32x4  __attribute__((ext_vector_type(4)));

#define MFMA_16x16x32(a,b,c) __builtin_amdgcn_mfma_f32_16x16x32_bf16((a),(b),(c),0,0,0)

__device__ __forceinline__ float bf2f(unsigned short u) {
    return __uint_as_float(((unsigned int)u) << 16);
}
__device__ __forceinline__ unsigned short f2bf(float f) {
    unsigned int u = __float_as_uint(f);
    return (unsigned short)((u + 0x7fffu + ((u >> 16) & 1u)) >> 16);
}
__device__ __forceinline__ float silu_f(float x) {
    return x / (1.0f + __expf(-x));
}

// ---------------------------------------------------------------------------
// Repack We1[0:128], We2, Wc1 (fp32 in global) into bf16 MFMA B-fragment order:
//   rep[((ct*4+ks)*64 + lane)*8 + j] = bf16(W[ks*32 + (lane>>4)*8 + j][ct*16 + (lane&15)])
// Also stash fp32 copies of small vectors (We1 row 256, biases, Wc2).
// ---------------------------------------------------------------------------
__global__ void repack_kernel(const float* __restrict__ We1,
                              const float* __restrict__ We2,
                              const float* __restrict__ Wc1,
                              const float* __restrict__ be1,
                              const float* __restrict__ be2,
                              const float* __restrict__ bc1,
                              const float* __restrict__ Wc2,
                              unsigned short* __restrict__ w1r,
                              unsigned short* __restrict__ w2r,
                              unsigned short* __restrict__ wc1r,
                              float* __restrict__ wlast,
                              float* __restrict__ be1f,
                              float* __restrict__ be2f,
                              float* __restrict__ bc1f,
                              float* __restrict__ wc2f) {
    int t = blockIdx.x * blockDim.x + threadIdx.x;
    if (t < 3 * 16384) {
        int m  = t / 16384;
        int e  = t % 16384;
        int j  = e & 7;
        int l  = (e >> 3) & 63;
        int ks = (e >> 9) & 3;
        int ct = e >> 11;
        int row = ks * 32 + (l >> 4) * 8 + j;
        int col = ct * 16 + (l & 15);
        const float*    src = (m == 0) ? We1 : ((m == 1) ? We2 : Wc1);
        unsigned short* dst = (m == 0) ? w1r : ((m == 1) ? w2r : wc1r);
        dst[e] = f2bf(src[row * 128 + col]);
    }
    if (t < 128) {
        wlast[t] = We1[256 * 128 + t];
        be1f[t]  = be1[t];
        be2f[t]  = be2[t];
        bc1f[t]  = bc1[t];
        wc2f[t]  = Wc2[t];
    }
}

// ---------------------------------------------------------------------------
// Q[b,c,h] = sum_k vnf[b,k,c] * We1[128+k, h]   (feat_V part of GEMM1, only
// B*C=300 distinct rows). fp32 in, fp32 out.
// ---------------------------------------------------------------------------
__global__ void q_kernel(const float* __restrict__ vnf,
                         const float* __restrict__ We1,
                         float* __restrict__ Q) {
    int t = blockIdx.x * blockDim.x + threadIdx.x;
    if (t >= NGRAPH * NCH * HD) return;
    int h  = t & 127;
    int bc = t >> 7;
    int b  = bc / NCH;
    int c  = bc % NCH;
    float s = 0.0f;
    for (int k = 0; k < 128; ++k)
        s += vnf[(b * 128 + k) * 3 + c] * We1[(128 + k) * 128 + h];
    Q[t] = s;
}

// ---------------------------------------------------------------------------
// Main fused kernel: 64 nodes/block, 256 threads (4 waves), 3125 blocks.
// ---------------------------------------------------------------------------
__global__ __launch_bounds__(256, 2) void egcl_main(
    const float* __restrict__ node_feat,   // [N,128] fp32
    const float* __restrict__ coord,       // [N,3]
    const float* __restrict__ vcoord,      // [B,3,C]
    const int*   __restrict__ batch,       // [N] sorted
    const unsigned short* __restrict__ w1r,
    const unsigned short* __restrict__ w2r,
    const unsigned short* __restrict__ wc1r,
    const float* __restrict__ Q,           // [B,C,H]
    const float* __restrict__ wlast,
    const float* __restrict__ be1f,
    const float* __restrict__ be2f,
    const float* __restrict__ bc1f,
    const float* __restrict__ wc2f,
    float* __restrict__ aggsum,            // [B,C,H]
    float* __restrict__ transsum,          // [B,3,C]
    float* __restrict__ cnt)               // [B]
{
    __shared__ __align__(16) unsigned short e_buf[EROWS * ESTR]; // 52224 B
    __shared__ float sdiff[BN][3][3];
    __shared__ float sradial[BN][3];
    __shared__ float s_s[EROWS];
    __shared__ int   sbatch[BN];
    __shared__ int   sseg_start[BN + 1];
    __shared__ int   sseg_b[BN];
    __shared__ int   snseg;

    const int tid   = threadIdx.x;
    const int wave  = tid >> 6;
    const int lane  = tid & 63;
    const int lrow  = lane & 15;           // MFMA row (A) / col (D) index
    const int lkb   = (lane >> 4) * 8;     // k-offset base within 32-wide K step
    const int rq    = (lane >> 4) * 4;     // D row-group base
    const int node0 = blockIdx.x * BN;

    // ---- Phase 0: per-node diff / radial / batch ----
    if (tid < BN) {
        int n = node0 + tid;
        int b = batch[n];
        sbatch[tid] = b;
        float cx = coord[n * 3 + 0];
        float cy = coord[n * 3 + 1];
        float cz = coord[n * 3 + 2];
        for (int c = 0; c < 3; ++c) {
            float dx = vcoord[b * 9 + 0 * 3 + c] - cx;
            float dy = vcoord[b * 9 + 1 * 3 + c] - cy;
            float dz = vcoord[b * 9 + 2 * 3 + c] - cz;
            sdiff[tid][0][c] = dx;
            sdiff[tid][1][c] = dy;
            sdiff[tid][2][c] = dz;
            sradial[tid][c] = sqrtf(dx * dx + dy * dy + dz * dz);
        }
    }
    __syncthreads();

    if (tid == 0) {   // segment scan (sorted batch); used only after later barriers
        int ns = 0, prev = -1;
        for (int i = 0; i < BN; ++i) {
            int b = sbatch[i];
            if (b != prev) { sseg_start[ns] = i; sseg_b[ns] = b; ++ns; prev = b; }
        }
        sseg_start[ns] = BN;
        snseg = ns;
    }

    // ---- GEMM1: P[64,128] = node_feat_tile @ We1_top; wave w -> rows 16w..16w+15
    f32x4 acc1[8] = {};
    {
        const float* arow = node_feat + (size_t)(node0 + wave * 16 + lrow) * 128;
        for (int ks = 0; ks < 4; ++ks) {
            f32x4 x0 = *(const f32x4*)(arow + ks * 32 + lkb);
            f32x4 x1 = *(const f32x4*)(arow + ks * 32 + lkb + 4);
            short8 af;
            af[0] = (short)f2bf(x0[0]); af[1] = (short)f2bf(x0[1]);
            af[2] = (short)f2bf(x0[2]); af[3] = (short)f2bf(x0[3]);
            af[4] = (short)f2bf(x1[0]); af[5] = (short)f2bf(x1[1]);
            af[6] = (short)f2bf(x1[2]); af[7] = (short)f2bf(x1[3]);
            for (int ct = 0; ct < 8; ++ct) {
                short8 bfg = *(const short8*)(w1r + ((ct * 4 + ks) * 64 + lane) * 8);
                acc1[ct] = MFMA_16x16x32(af, bfg, acc1[ct]);
            }
        }
    }
    // Epilogue 1: E1[(3n+c), h] = silu(P + Q[b,c,h] + radial*wlast[h] + be1[h])
    for (int ct = 0; ct < 8; ++ct) {
        int h = ct * 16 + lrow;
        float wl = wlast[h];
        float bb = be1f[h];
        for (int r = 0; r < 4; ++r) {
            int nl = wave * 16 + rq + r;
            int b  = sbatch[nl];
            float p = acc1[ct][r] + bb;
            for (int c = 0; c < 3; ++c) {
                float x = p + Q[(b * 3 + c) * 128 + h] + sradial[nl][c] * wl;
                e_buf[(3 * nl + c) * ESTR + h] = f2bf(silu_f(x));
            }
        }
    }
    __syncthreads();

    // ---- GEMM2: M = silu(E1 @ We2 + be2); wave w -> rows 48w..48w+47 ----
    f32x4 acc2[3][8] = {};
    for (int ks = 0; ks < 4; ++ks) {
        short8 af[3];
        for (int i = 0; i < 3; ++i)
            af[i] = *(const short8*)(&e_buf[((wave * 3 + i) * 16 + lrow) * ESTR +
                                            ks * 32 + lkb]);
        for (int ct = 0; ct < 8; ++ct) {
            short8 bfg = *(const short8*)(w2r + ((ct * 4 + ks) * 64 + lane) * 8);
            for (int i = 0; i < 3; ++i)
                acc2[i][ct] = MFMA_16x16x32(af[i], bfg, acc2[i][ct]);
        }
    }
    __syncthreads();
    for (int i = 0; i < 3; ++i) {
        for (int ct = 0; ct < 8; ++ct) {
            int h = ct * 16 + lrow;
            float bb = be2f[h];
            for (int r = 0; r < 4; ++r) {
                int row = (wave * 3 + i) * 16 + rq + r;
                e_buf[row * ESTR + h] = f2bf(silu_f(acc2[i][ct][r] + bb));
            }
        }
    }
    __syncthreads();

    // ---- GEMM3: SH = silu(M @ Wc1 + bc1); s = SH . Wc2 (never materialized) ----
    f32x4 acc3[3][8] = {};
    for (int ks = 0; ks < 4; ++ks) {
        short8 af[3];
        for (int i = 0; i < 3; ++i)
            af[i] = *(const short8*)(&e_buf[((wave * 3 + i) * 16 + lrow) * ESTR +
                                            ks * 32 + lkb]);
        for (int ct = 0; ct < 8; ++ct) {
            short8 bfg = *(const short8*)(wc1r + ((ct * 4 + ks) * 64 + lane) * 8);
            for (int i = 0; i < 3; ++i)
                acc3[i][ct] = MFMA_16x16x32(af[i], bfg, acc3[i][ct]);
        }
    }
    for (int i = 0; i < 3; ++i) {
        float p0 = 0.f, p1 = 0.f, p2 = 0.f, p3 = 0.f;
        for (int ct = 0; ct < 8; ++ct) {
            int h = ct * 16 + lrow;
            float bb = bc1f[h];
            float w2 = wc2f[h];
            p0 += silu_f(acc3[i][ct][0] + bb) * w2;
            p1 += silu_f(acc3[i][ct][1] + bb) * w2;
            p2 += silu_f(acc3[i][ct][2] + bb) * w2;
            p3 += silu_f(acc3[i][ct][3] + bb) * w2;
        }
        for (int off = 1; off < 16; off <<= 1) {   // reduce over the 16 col-lanes
            p0 += __shfl_xor(p0, off, 64);
            p1 += __shfl_xor(p1, off, 64);
            p2 += __shfl_xor(p2, off, 64);
            p3 += __shfl_xor(p3, off, 64);
        }
        if (lrow == 0) {
            int rbase = (wave * 3 + i) * 16 + rq;
            s_s[rbase + 0] = p0;
            s_s[rbase + 1] = p1;
            s_s[rbase + 2] = p2;
            s_s[rbase + 3] = p3;
        }
    }
    __syncthreads();

    // ---- Reduce: per contiguous segment, block-local sums then atomics ----
    int nseg = snseg;
    for (int sg = 0; sg < nseg; ++sg) {
        int s0 = sseg_start[sg], s1 = sseg_start[sg + 1], b = sseg_b[sg];
        for (int idx = tid; idx < NCH * HD; idx += 256) {
            int c = idx >> 7, h = idx & 127;
            float sum = 0.f;
            for (int i = s0; i < s1; ++i)
                sum += bf2f(e_buf[(3 * i + c) * ESTR + h]);
            atomicAdd(&aggsum[(b * 3 + c) * 128 + h], sum);
        }
        if (tid < 9) {
            int d = tid / 3, c = tid % 3;
            float sum = 0.f;
            for (int i = s0; i < s1; ++i)
                sum += sdiff[i][d][c] * s_s[3 * i + c];
            atomicAdd(&transsum[b * 9 + d * 3 + c], sum);
        }
        if (tid == 0) atomicAdd(&cnt[b], (float)(s1 - s0));
    }
}

// ---------------------------------------------------------------------------
// Finalize: one block per (b,c) row. Means, node model, residuals, outputs.
// All fp32.
// ---------------------------------------------------------------------------
__global__ void finalize_kernel(const float* __restrict__ vnf,
                                const float* __restrict__ vcoord,
                                const float* __restrict__ Wn1,
                                const float* __restrict__ bn1,
                                const float* __restrict__ Wn2,
                                const float* __restrict__ bn2,
                                const float* __restrict__ aggsum,
                                const float* __restrict__ transsum,
                                const float* __restrict__ cnt,
                                float* __restrict__ out) {
    int b = blockIdx.x / NCH;
    int c = blockIdx.x % NCH;
    int j = threadIdx.x;   // 0..127
    __shared__ float nin[256];
    __shared__ float h1[128];
    float count = fmaxf(cnt[b], 1.0f);
    nin[j]       = vnf[(b * 128 + j) * 3 + c];
    nin[128 + j] = aggsum[(b * 3 + c) * 128 + j] / count;
    __syncthreads();
    float x = bn1[j];
    for (int k = 0; k < 256; ++k)
        x += nin[k] * Wn1[k * 128 + j];
    h1[j] = silu_f(x);
    __syncthreads();
    float y = bn2[j];
    for (int k = 0; k < 128; ++k)
        y += h1[k] * Wn2[k * 128 + j];
    out[(b * 128 + j) * 3 + c] = vnf[(b * 128 + j) * 3 + c] + y;
    if (c == 0 && j < 9) {
        out[NGRAPH * 128 * 3 + b * 9 + j] =
            vcoord[b * 9 + j] + transsum[b * 9 + j] / count;
    }
}

// ---------------------------------------------------------------------------
extern "C" void kernel_launch(void* const* d_in, const int* in_sizes, int n_in,
                              void* d_out, int out_size, void* d_ws, size_t ws_size,
                              hipStream_t stream) {
    const float* node_feat = (const float*)d_in[0];
    const float* coord     = (const float*)d_in[1];
    const float* vnf       = (const float*)d_in[2];
    const float* vcoord    = (const float*)d_in[3];
    const int*   batch     = (const int*)d_in[4];
    const float* We1 = (const float*)d_in[5];
    const float* be1 = (const float*)d_in[6];
    const float* We2 = (const float*)d_in[7];
    const float* be2 = (const float*)d_in[8];
    const float* Wc1 = (const float*)d_in[9];
    const float* bc1 = (const float*)d_in[10];
    const float* Wc2 = (const float*)d_in[11];
    const float* Wn1 = (const float*)d_in[12];
    const float* bn1 = (const float*)d_in[13];
    const float* Wn2 = (const float*)d_in[14];
    const float* bn2 = (const float*)d_in[15];

    char* ws = (char*)d_ws;
    // workspace layout (bytes)
    float*          aggsum   = (float*)(ws + 0);          // 100*3*128*4 = 153600
    float*          transsum = (float*)(ws + 153600);     // 100*9*4     = 3600
    float*          cntp     = (float*)(ws + 157200);     // 100*4       = 400
    float*          Q        = (float*)(ws + 157600);     // 153600
    unsigned short* w1r      = (unsigned short*)(ws + 311200); // 32768
    unsigned short* w2r      = (unsigned short*)(ws + 343968); // 32768
    unsigned short* wc1r     = (unsigned short*)(ws + 376736); // 32768
    float*          wlast    = (float*)(ws + 409504);     // 512
    float*          be1f     = (float*)(ws + 410016);
    float*          be2f     = (float*)(ws + 410528);
    float*          bc1f     = (float*)(ws + 411040);
    float*          wc2f     = (float*)(ws + 411552);

    (void)hipMemsetAsync(d_ws, 0, 157600, stream);  // zero accumulators each call

    repack_kernel<<<(3 * 16384 + 255) / 256, 256, 0, stream>>>(
        We1, We2, Wc1, be1, be2, bc1, Wc2,
        w1r, w2r, wc1r, wlast, be1f, be2f, bc1f, wc2f);

    q_kernel<<<(NGRAPH * NCH * HD + 255) / 256, 256, 0, stream>>>(vnf, We1, Q);

    egcl_main<<<NNODES / BN, 256, 0, stream>>>(
        node_feat, coord, vcoord, batch, w1r, w2r, wc1r, Q,
        wlast, be1f, be2f, bc1f, wc2f, aggsum, transsum, cntp);

    finalize_kernel<<<NGRAPH * NCH, 128, 0, stream>>>(
        vnf, vcoord, Wn1, bn1, Wn2, bn2, aggsum, transsum, cntp,
        (float*)d_out);
}